// Round 1
// baseline (2325.352 us; speedup 1.0000x reference)
//
#include <hip/hip_runtime.h>
#include <hip/hip_bf16.h>

// ---------------------------------------------------------------------------
// CFGSubASTExpressionCombiner: gather -> QKV proj (bf16 MFMA) -> segment
// softmax (shift-free, atomics) -> pooled -> output GEMM.
// D = 256, H = 8, HD = 32, OUT = 256 (hard-coded dims; row counts runtime).
// ---------------------------------------------------------------------------

typedef __attribute__((ext_vector_type(8))) short bf16x8;
typedef __attribute__((ext_vector_type(4))) float f32x4;

#define DEV __device__ __forceinline__

DEV float bf2f(unsigned short u) {
    union { unsigned int i; float f; } x;
    x.i = ((unsigned int)u) << 16;
    return x.f;
}

DEV unsigned short f2bf(float f) {
    union { float f; unsigned int i; } x;
    x.f = f;
    unsigned int i = x.i;
    unsigned int r = 0x7fffu + ((i >> 16) & 1u);   // round-to-nearest-even
    return (unsigned short)((i + r) >> 16);
}

// ---------------------------------------------------------------------------
// Weight prep: transpose fp32 weights into bf16 [N][K] (K contiguous) layout,
// and concatenate b_k|b_v.
// ---------------------------------------------------------------------------
__global__ void convert_weights(const float* __restrict__ Wq,
                                const float* __restrict__ Wk,
                                const float* __restrict__ Wv,
                                const float* __restrict__ Wo,
                                const float* __restrict__ bk,
                                const float* __restrict__ bv,
                                unsigned short* __restrict__ Wtq,
                                unsigned short* __restrict__ Wtkv,
                                unsigned short* __restrict__ Wto,
                                float* __restrict__ bkv) {
    int t = blockIdx.x * 256 + threadIdx.x;
    if (t < 65536) {                       // Wtq[n][k] = Wq[k][n]
        int n = t >> 8, k = t & 255;
        Wtq[t] = f2bf(Wq[k * 256 + n]);
    } else if (t < 65536 + 131072) {       // Wtkv[n][k]: n<256 -> Wk, else Wv
        int u = t - 65536;
        int n = u >> 8, k = u & 255;
        Wtkv[u] = f2bf(n < 256 ? Wk[k * 256 + n] : Wv[k * 256 + (n - 256)]);
    } else if (t < 65536 + 131072 + 65536) {  // Wto[n][k] = Wo[k][n]
        int u = t - 196608;
        int n = u >> 8, k = u & 255;
        Wto[u] = f2bf(Wo[k * 256 + n]);
    } else if (t < 262144 + 512) {
        int c = t - 262144;
        bkv[c] = c < 256 ? bk[c] : bv[c - 256];
    }
}

// ---------------------------------------------------------------------------
// Generic projection GEMM: Out[dst(r)][n] = sum_k A[src(r)][k] * Wt[n][k] + bias[n]
// Tile 128x128, K = 256 in 4 steps of 64. 4 waves, each owns a 64x64 quadrant.
// A: fp32 (converted to bf16 on load) or bf16. Out: bf16 or fp32.
// LDS rows padded to 72 bf16 (144 B, 16B-aligned) to break bank-conflict stride.
// ---------------------------------------------------------------------------
template <bool GATHER, bool SCATTER, bool A_BF16, bool OUT_F32>
__global__ __launch_bounds__(256) void gemm_proj(
    const void* __restrict__ Aptr,
    const int* __restrict__ srcIdx,
    const int* __restrict__ dstIdx,
    const unsigned short* __restrict__ Wt,   // bf16 [N][256]
    const float* __restrict__ bias,          // [N]
    void* __restrict__ Out,
    int nrows, int ldo) {
    __shared__ unsigned short Alds[128][72];
    __shared__ unsigned short Blds[128][72];

    const int tn = blockIdx.x, tm = blockIdx.y;
    const int tid = threadIdx.x;
    const int wave = tid >> 6, lane = tid & 63;
    const int wm = wave >> 1, wn = wave & 1;

    f32x4 acc[4][4] = {};

    for (int kt = 0; kt < 4; ++kt) {
        const int k0 = kt * 64;

        // ---- load A tile (128 rows x 64 k) ----
        if constexpr (!A_BF16) {
            const int c4 = (tid & 15) * 4;
            const int rbase = tid >> 4;
#pragma unroll
            for (int p = 0; p < 8; ++p) {
                int r = p * 16 + rbase;
                int gr = tm * 128 + r;
                long src;
                if (gr < nrows) src = GATHER ? (long)srcIdx[gr] : (long)gr;
                else            src = 0;
                const float4 v = *(const float4*)((const float*)Aptr + src * 256 + k0 + c4);
                unsigned int lo = (unsigned int)f2bf(v.x) | ((unsigned int)f2bf(v.y) << 16);
                unsigned int hi = (unsigned int)f2bf(v.z) | ((unsigned int)f2bf(v.w) << 16);
                *(uint2*)(&Alds[r][c4]) = make_uint2(lo, hi);
            }
        } else {
            const int c8 = (tid & 7) * 8;
            const int rbase = tid >> 3;
#pragma unroll
            for (int p = 0; p < 4; ++p) {
                int r = p * 32 + rbase;
                int gr = tm * 128 + r;
                long src = (gr < nrows) ? (long)gr : 0;
                const uint4 v = *(const uint4*)((const unsigned short*)Aptr + src * 256 + k0 + c8);
                *(uint4*)(&Alds[r][c8]) = v;
            }
        }

        // ---- load B tile (128 cols x 64 k) from Wt ----
        {
            const int c8 = (tid & 7) * 8;
            const int nbase = tid >> 3;
#pragma unroll
            for (int p = 0; p < 4; ++p) {
                int n = p * 32 + nbase;
                long gn = (long)tn * 128 + n;
                const uint4 v = *(const uint4*)(Wt + gn * 256 + k0 + c8);
                *(uint4*)(&Blds[n][c8]) = v;
            }
        }

        __syncthreads();

        // ---- MFMA ----
#pragma unroll
        for (int ks = 0; ks < 2; ++ks) {
            const int kb = ks * 32 + (lane >> 4) * 8;
            bf16x8 a[4], b[4];
#pragma unroll
            for (int i = 0; i < 4; ++i)
                a[i] = *(const bf16x8*)(&Alds[wm * 64 + i * 16 + (lane & 15)][kb]);
#pragma unroll
            for (int i = 0; i < 4; ++i)
                b[i] = *(const bf16x8*)(&Blds[wn * 64 + i * 16 + (lane & 15)][kb]);
#pragma unroll
            for (int i = 0; i < 4; ++i)
#pragma unroll
                for (int j = 0; j < 4; ++j)
                    acc[i][j] = __builtin_amdgcn_mfma_f32_16x16x32_bf16(a[i], b[j], acc[i][j], 0, 0, 0);
        }

        __syncthreads();
    }

    // ---- epilogue ----
#pragma unroll
    for (int i = 0; i < 4; ++i) {
#pragma unroll
        for (int j = 0; j < 4; ++j) {
            const int col = tn * 128 + wn * 64 + j * 16 + (lane & 15);
            const float bs = bias[col];
#pragma unroll
            for (int rj = 0; rj < 4; ++rj) {
                const int row = tm * 128 + wm * 64 + i * 16 + (lane >> 4) * 4 + rj;
                if (row < nrows) {
                    long drow = SCATTER ? (long)dstIdx[row] : (long)row;
                    float val = acc[i][j][rj] + bs;
                    if constexpr (OUT_F32)
                        ((float*)Out)[drow * ldo + col] = val;
                    else
                        ((unsigned short*)Out)[drow * ldo + col] = f2bf(val);
                }
            }
        }
    }
}

// ---------------------------------------------------------------------------
// Pooling: one wave per mapping entry m.
//   s = segid[m]; score_h = <k[m,h,:], q[s,h,:]> * scale; ew = exp(score)
//   pooled[s,:] += ew_h * v[m,:];  denom[s,h] += ew_h
// Shift-free softmax: scores have |s| <~ 1, exp is safe without max-subtract.
// ---------------------------------------------------------------------------
__global__ __launch_bounds__(256) void pool_kernel(
    const unsigned short* __restrict__ q,    // bf16 [S][256]
    const unsigned short* __restrict__ kv,   // bf16 [M][512] (k | v)
    const int* __restrict__ segid,           // [M]
    float* __restrict__ pooled,              // [S][256] (zeroed)
    float* __restrict__ denom,               // [S][8]   (zeroed)
    int M) {
    const int m = blockIdx.x * 4 + (threadIdx.x >> 6);
    if (m >= M) return;
    const int lane = threadIdx.x & 63;
    const int s = segid[m];

    const ushort4 qv = *(const ushort4*)(q + (long)s * 256 + lane * 4);
    const ushort4 kk = *(const ushort4*)(kv + (long)m * 512 + lane * 4);
    float partial = bf2f(qv.x) * bf2f(kk.x) + bf2f(qv.y) * bf2f(kk.y) +
                    bf2f(qv.z) * bf2f(kk.z) + bf2f(qv.w) * bf2f(kk.w);
    partial += __shfl_xor(partial, 1);
    partial += __shfl_xor(partial, 2);
    partial += __shfl_xor(partial, 4);   // all 8 lanes of a head group have the dot

    const float ew = expf(partial * 0.17677669529663687f);  // 1/sqrt(32)

    const ushort4 vv = *(const ushort4*)(kv + (long)m * 512 + 256 + lane * 4);
    float* pp = pooled + (long)s * 256 + lane * 4;
    unsafeAtomicAdd(pp + 0, ew * bf2f(vv.x));
    unsafeAtomicAdd(pp + 1, ew * bf2f(vv.y));
    unsafeAtomicAdd(pp + 2, ew * bf2f(vv.z));
    unsafeAtomicAdd(pp + 3, ew * bf2f(vv.w));
    if ((lane & 7) == 0)
        unsafeAtomicAdd(denom + (long)s * 8 + (lane >> 3), ew);
}

// ---------------------------------------------------------------------------
// Finalize: pooledn[s][d] = pooled[s][d] / max(denom[s][d/32], 1e-9) as bf16
// ---------------------------------------------------------------------------
__global__ __launch_bounds__(256) void finalize_kernel(
    const float* __restrict__ pooled,
    const float* __restrict__ denom,
    unsigned short* __restrict__ pooledn,
    int S) {
    const int t = blockIdx.x * 256 + threadIdx.x;   // one thread per 4 elems
    if (t >= S * 64) return;
    const int s = t >> 6;
    const int c4 = (t & 63) * 4;
    const float4 p = *(const float4*)(pooled + (long)s * 256 + c4);
    const float dn = denom[s * 8 + (c4 >> 5)];
    const float w = 1.0f / fmaxf(dn, 1e-9f);
    ushort4 o;
    o.x = f2bf(p.x * w);
    o.y = f2bf(p.y * w);
    o.z = f2bf(p.z * w);
    o.w = f2bf(p.w * w);
    *(ushort4*)(pooledn + (long)s * 256 + c4) = o;
}

// ---------------------------------------------------------------------------
extern "C" void kernel_launch(void* const* d_in, const int* in_sizes, int n_in,
                              void* d_out, int out_size, void* d_ws, size_t ws_size,
                              hipStream_t stream) {
    const float* enc  = (const float*)d_in[0];
    const float* W_q  = (const float*)d_in[1];
    const float* b_q  = (const float*)d_in[2];
    const float* W_k  = (const float*)d_in[3];
    const float* b_k  = (const float*)d_in[4];
    const float* W_v  = (const float*)d_in[5];
    const float* b_v  = (const float*)d_in[6];
    const float* W_o  = (const float*)d_in[7];
    const float* b_o  = (const float*)d_in[8];
    const int* map_key = (const int*)d_in[9];    // [M] ast idx
    const int* map_val = (const int*)d_in[10];   // [M] cfg idx (segment id)
    const int* pdg_key = (const int*)d_in[11];   // [S] dst rows (bijection)
    const int* pdg_val = (const int*)d_in[12];   // [S] src ast rows

    const int M = in_sizes[9];
    const int S = in_sizes[11];

    char* ws = (char*)d_ws;
    size_t off = 0;
    auto alloc = [&](size_t bytes) -> char* {
        char* p = ws + off;
        off += (bytes + 255) & ~(size_t)255;
        return p;
    };

    unsigned short* Wt_q  = (unsigned short*)alloc(256 * 256 * 2);
    unsigned short* Wt_kv = (unsigned short*)alloc(512 * 256 * 2);
    unsigned short* Wt_o  = (unsigned short*)alloc(256 * 256 * 2);
    float*          b_kv  = (float*)alloc(512 * 4);
    unsigned short* qbuf  = (unsigned short*)alloc((size_t)S * 256 * 2);  // q, then pooledn
    unsigned short* kvbuf = (unsigned short*)alloc((size_t)M * 512 * 2);
    float*          pooled = (float*)alloc((size_t)S * 256 * 4);
    float*          denom  = (float*)alloc((size_t)S * 8 * 4);

    // zero accumulators + q (uncovered scatter rows must read as 0)
    hipMemsetAsync(qbuf, 0, (size_t)S * 256 * 2, stream);
    hipMemsetAsync(pooled, 0, (size_t)S * 256 * 4, stream);
    hipMemsetAsync(denom, 0, (size_t)S * 8 * 4, stream);

    convert_weights<<<(262144 + 512 + 255) / 256, 256, 0, stream>>>(
        W_q, W_k, W_v, W_o, b_k, b_v, Wt_q, Wt_kv, Wt_o, b_kv);

    // Q projection: q[pdg_key[i]] = enc[pdg_val[i]] @ W_q + b_q
    dim3 gq(2, (S + 127) / 128);
    gemm_proj<true, true, false, false><<<gq, 256, 0, stream>>>(
        enc, pdg_val, pdg_key, Wt_q, b_q, qbuf, S, 256);

    // K|V projection: kv[m] = enc[map_key[m]] @ [W_k | W_v] + [b_k | b_v]
    dim3 gkv(4, (M + 127) / 128);
    gemm_proj<true, false, false, false><<<gkv, 256, 0, stream>>>(
        enc, map_key, nullptr, Wt_kv, b_kv, kvbuf, M, 512);

    // segment softmax + weighted pooling
    pool_kernel<<<(M + 3) / 4, 256, 0, stream>>>(qbuf, kvbuf, map_val, pooled, denom, M);

    // normalize -> bf16 (reuse qbuf)
    finalize_kernel<<<(S * 64 + 255) / 256, 256, 0, stream>>>(pooled, denom, qbuf, S);

    // output projection to d_out (fp32)
    dim3 go(2, (S + 127) / 128);
    gemm_proj<false, false, true, true><<<go, 256, 0, stream>>>(
        qbuf, nullptr, nullptr, Wt_o, b_o, d_out, S, 256);
}

// Round 2
// 1213.584 us; speedup vs baseline: 1.9161x; 1.9161x over previous
//
#include <hip/hip_runtime.h>
#include <hip/hip_bf16.h>

// ---------------------------------------------------------------------------
// CFGSubASTExpressionCombiner: gather -> QKV proj (bf16 MFMA) -> counting-sort
// by segment -> CSR segment softmax+pool (no atomics) -> output GEMM.
// D = 256, H = 8, HD = 32, OUT = 256.
// ---------------------------------------------------------------------------

typedef __attribute__((ext_vector_type(8))) short bf16x8;
typedef __attribute__((ext_vector_type(4))) float f32x4;

#define DEV __device__ __forceinline__

DEV float bf2f(unsigned short u) {
    union { unsigned int i; float f; } x;
    x.i = ((unsigned int)u) << 16;
    return x.f;
}

DEV unsigned short f2bf(float f) {
    union { float f; unsigned int i; } x;
    x.f = f;
    unsigned int i = x.i;
    unsigned int r = 0x7fffu + ((i >> 16) & 1u);   // round-to-nearest-even
    return (unsigned short)((i + r) >> 16);
}

// ---------------------------------------------------------------------------
// Weight prep: transpose fp32 weights into bf16 [N][K] (K contiguous) layout,
// and concatenate b_k|b_v.
// ---------------------------------------------------------------------------
__global__ void convert_weights(const float* __restrict__ Wq,
                                const float* __restrict__ Wk,
                                const float* __restrict__ Wv,
                                const float* __restrict__ Wo,
                                const float* __restrict__ bk,
                                const float* __restrict__ bv,
                                unsigned short* __restrict__ Wtq,
                                unsigned short* __restrict__ Wtkv,
                                unsigned short* __restrict__ Wto,
                                float* __restrict__ bkv) {
    int t = blockIdx.x * 256 + threadIdx.x;
    if (t < 65536) {                       // Wtq[n][k] = Wq[k][n]
        int n = t >> 8, k = t & 255;
        Wtq[t] = f2bf(Wq[k * 256 + n]);
    } else if (t < 65536 + 131072) {       // Wtkv[n][k]: n<256 -> Wk, else Wv
        int u = t - 65536;
        int n = u >> 8, k = u & 255;
        Wtkv[u] = f2bf(n < 256 ? Wk[k * 256 + n] : Wv[k * 256 + (n - 256)]);
    } else if (t < 65536 + 131072 + 65536) {  // Wto[n][k] = Wo[k][n]
        int u = t - 196608;
        int n = u >> 8, k = u & 255;
        Wto[u] = f2bf(Wo[k * 256 + n]);
    } else if (t < 262144 + 512) {
        int c = t - 262144;
        bkv[c] = c < 256 ? bk[c] : bv[c - 256];
    }
}

// ---------------------------------------------------------------------------
// Counting sort of mapping entries by segment id.
// ---------------------------------------------------------------------------
__global__ void hist_kernel(const int* __restrict__ map_val,
                            int* __restrict__ counts, int M) {
    int m = blockIdx.x * 256 + threadIdx.x;
    if (m < M) atomicAdd(&counts[map_val[m]], 1);
}

// Single-block exclusive scan over counts[S] -> offsets[S+1].
__global__ __launch_bounds__(1024) void scan_kernel(const int* __restrict__ counts,
                                                    int* __restrict__ offsets, int S) {
    __shared__ int part[1024];
    const int t = threadIdx.x;
    const int chunk = (S + 1023) / 1024;
    const int lo = t * chunk;
    const int hi = min(lo + chunk, S);
    int sum = 0;
    for (int i = lo; i < hi; ++i) sum += counts[i];
    part[t] = sum;
    __syncthreads();
    for (int d = 1; d < 1024; d <<= 1) {
        int v = (t >= d) ? part[t - d] : 0;
        __syncthreads();
        part[t] += v;
        __syncthreads();
    }
    int run = (t > 0) ? part[t - 1] : 0;
    for (int i = lo; i < hi; ++i) {
        offsets[i] = run;
        run += counts[i];
    }
    if (t == 1023) offsets[S] = part[1023];
}

__global__ void scatter_kernel(const int* __restrict__ map_key,
                               const int* __restrict__ map_val,
                               const int* __restrict__ offsets,
                               int* __restrict__ cursor,
                               int* __restrict__ sorted_src, int M) {
    int m = blockIdx.x * 256 + threadIdx.x;
    if (m >= M) return;
    int seg = map_val[m];
    int pos = offsets[seg] + atomicAdd(&cursor[seg], 1);
    sorted_src[pos] = map_key[m];
}

// ---------------------------------------------------------------------------
// Generic projection GEMM: Out[dst(r)][n] = sum_k A[src(r)][k] * Wt[n][k] + bias[n]
// Tile 128x128, K = 256 in 4 steps of 64. 4 waves, each owns a 64x64 quadrant.
// ---------------------------------------------------------------------------
template <bool GATHER, bool SCATTER, bool A_BF16, bool OUT_F32>
__global__ __launch_bounds__(256) void gemm_proj(
    const void* __restrict__ Aptr,
    const int* __restrict__ srcIdx,
    const int* __restrict__ dstIdx,
    const unsigned short* __restrict__ Wt,   // bf16 [N][256]
    const float* __restrict__ bias,          // [N]
    void* __restrict__ Out,
    int nrows, int ldo) {
    __shared__ unsigned short Alds[128][72];
    __shared__ unsigned short Blds[128][72];

    const int tn = blockIdx.x, tm = blockIdx.y;
    const int tid = threadIdx.x;
    const int wave = tid >> 6, lane = tid & 63;
    const int wm = wave >> 1, wn = wave & 1;

    f32x4 acc[4][4] = {};

    for (int kt = 0; kt < 4; ++kt) {
        const int k0 = kt * 64;

        // ---- load A tile (128 rows x 64 k) ----
        if constexpr (!A_BF16) {
            const int c4 = (tid & 15) * 4;
            const int rbase = tid >> 4;
#pragma unroll
            for (int p = 0; p < 8; ++p) {
                int r = p * 16 + rbase;
                int gr = tm * 128 + r;
                long src;
                if (gr < nrows) src = GATHER ? (long)srcIdx[gr] : (long)gr;
                else            src = 0;
                const float4 v = *(const float4*)((const float*)Aptr + src * 256 + k0 + c4);
                unsigned int lo = (unsigned int)f2bf(v.x) | ((unsigned int)f2bf(v.y) << 16);
                unsigned int hi = (unsigned int)f2bf(v.z) | ((unsigned int)f2bf(v.w) << 16);
                *(uint2*)(&Alds[r][c4]) = make_uint2(lo, hi);
            }
        } else {
            const int c8 = (tid & 7) * 8;
            const int rbase = tid >> 3;
#pragma unroll
            for (int p = 0; p < 4; ++p) {
                int r = p * 32 + rbase;
                int gr = tm * 128 + r;
                long src = (gr < nrows) ? (long)gr : 0;
                const uint4 v = *(const uint4*)((const unsigned short*)Aptr + src * 256 + k0 + c8);
                *(uint4*)(&Alds[r][c8]) = v;
            }
        }

        // ---- load B tile (128 cols x 64 k) from Wt ----
        {
            const int c8 = (tid & 7) * 8;
            const int nbase = tid >> 3;
#pragma unroll
            for (int p = 0; p < 4; ++p) {
                int n = p * 32 + nbase;
                long gn = (long)tn * 128 + n;
                const uint4 v = *(const uint4*)(Wt + gn * 256 + k0 + c8);
                *(uint4*)(&Blds[n][c8]) = v;
            }
        }

        __syncthreads();

        // ---- MFMA ----
#pragma unroll
        for (int ks = 0; ks < 2; ++ks) {
            const int kb = ks * 32 + (lane >> 4) * 8;
            bf16x8 a[4], b[4];
#pragma unroll
            for (int i = 0; i < 4; ++i)
                a[i] = *(const bf16x8*)(&Alds[wm * 64 + i * 16 + (lane & 15)][kb]);
#pragma unroll
            for (int i = 0; i < 4; ++i)
                b[i] = *(const bf16x8*)(&Blds[wn * 64 + i * 16 + (lane & 15)][kb]);
#pragma unroll
            for (int i = 0; i < 4; ++i)
#pragma unroll
                for (int j = 0; j < 4; ++j)
                    acc[i][j] = __builtin_amdgcn_mfma_f32_16x16x32_bf16(a[i], b[j], acc[i][j], 0, 0, 0);
        }

        __syncthreads();
    }

    // ---- epilogue ----
#pragma unroll
    for (int i = 0; i < 4; ++i) {
#pragma unroll
        for (int j = 0; j < 4; ++j) {
            const int col = tn * 128 + wn * 64 + j * 16 + (lane & 15);
            const float bs = bias[col];
#pragma unroll
            for (int rj = 0; rj < 4; ++rj) {
                const int row = tm * 128 + wm * 64 + i * 16 + (lane >> 4) * 4 + rj;
                if (row < nrows) {
                    long drow = SCATTER ? (long)dstIdx[row] : (long)row;
                    float val = acc[i][j][rj] + bs;
                    if constexpr (OUT_F32)
                        ((float*)Out)[drow * ldo + col] = val;
                    else
                        ((unsigned short*)Out)[drow * ldo + col] = f2bf(val);
                }
            }
        }
    }
}

// ---------------------------------------------------------------------------
// CSR pooling: one wave per segment s. kv rows for segment s are contiguous
// [offsets[s], offsets[s+1]) because the KV GEMM gathered in sorted order.
//   score_h = <k[e,h,:], q[s,h,:]> * scale ; ew = exp(score)  (shift-free)
//   acc += ew * v[e,:] ; denom_h += ew ; out[s] = bf16(acc / max(denom,1e-9))
// ---------------------------------------------------------------------------
__global__ __launch_bounds__(256) void pool_csr_kernel(
    const unsigned short* __restrict__ q,    // bf16 [S][256]
    const unsigned short* __restrict__ kv,   // bf16 [Msorted][512] (k | v)
    const int* __restrict__ offsets,         // [S+1]
    unsigned short* __restrict__ out,        // bf16 [S][256]
    int S) {
    const int s = blockIdx.x * 4 + (threadIdx.x >> 6);
    if (s >= S) return;
    const int lane = threadIdx.x & 63;
    const int beg = offsets[s];
    const int end = offsets[s + 1];

    const ushort4 qv = *(const ushort4*)(q + (long)s * 256 + lane * 4);
    const float q0 = bf2f(qv.x), q1 = bf2f(qv.y), q2 = bf2f(qv.z), q3 = bf2f(qv.w);

    float a0 = 0.f, a1 = 0.f, a2 = 0.f, a3 = 0.f, denom = 0.f;

    for (int e = beg; e < end; ++e) {
        const ushort4 kk = *(const ushort4*)(kv + (long)e * 512 + lane * 4);
        const ushort4 vv = *(const ushort4*)(kv + (long)e * 512 + 256 + lane * 4);
        float p = q0 * bf2f(kk.x) + q1 * bf2f(kk.y) + q2 * bf2f(kk.z) + q3 * bf2f(kk.w);
        p += __shfl_xor(p, 1);
        p += __shfl_xor(p, 2);
        p += __shfl_xor(p, 4);   // all 8 lanes of the head group hold the dot
        const float ew = expf(p * 0.17677669529663687f);  // 1/sqrt(32)
        a0 += ew * bf2f(vv.x);
        a1 += ew * bf2f(vv.y);
        a2 += ew * bf2f(vv.z);
        a3 += ew * bf2f(vv.w);
        denom += ew;
    }

    const float w = 1.0f / fmaxf(denom, 1e-9f);
    ushort4 o;
    o.x = f2bf(a0 * w);
    o.y = f2bf(a1 * w);
    o.z = f2bf(a2 * w);
    o.w = f2bf(a3 * w);
    *(ushort4*)(out + (long)s * 256 + lane * 4) = o;
}

// ---------------------------------------------------------------------------
extern "C" void kernel_launch(void* const* d_in, const int* in_sizes, int n_in,
                              void* d_out, int out_size, void* d_ws, size_t ws_size,
                              hipStream_t stream) {
    const float* enc  = (const float*)d_in[0];
    const float* W_q  = (const float*)d_in[1];
    const float* b_q  = (const float*)d_in[2];
    const float* W_k  = (const float*)d_in[3];
    const float* b_k  = (const float*)d_in[4];
    const float* W_v  = (const float*)d_in[5];
    const float* b_v  = (const float*)d_in[6];
    const float* W_o  = (const float*)d_in[7];
    const float* b_o  = (const float*)d_in[8];
    const int* map_key = (const int*)d_in[9];    // [M] ast idx
    const int* map_val = (const int*)d_in[10];   // [M] cfg idx (segment id)
    const int* pdg_key = (const int*)d_in[11];   // [S] dst rows (bijection)
    const int* pdg_val = (const int*)d_in[12];   // [S] src ast rows

    const int M = in_sizes[9];
    const int S = in_sizes[11];

    char* ws = (char*)d_ws;
    size_t off = 0;
    auto alloc = [&](size_t bytes) -> char* {
        char* p = ws + off;
        off += (bytes + 255) & ~(size_t)255;
        return p;
    };

    unsigned short* Wt_q  = (unsigned short*)alloc(256 * 256 * 2);
    unsigned short* Wt_kv = (unsigned short*)alloc(512 * 256 * 2);
    unsigned short* Wt_o  = (unsigned short*)alloc(256 * 256 * 2);
    float*          b_kv  = (float*)alloc(512 * 4);
    int*            counts  = (int*)alloc((size_t)S * 4);
    int*            cursor  = (int*)alloc((size_t)S * 4);
    int*            offsets = (int*)alloc((size_t)(S + 1) * 4);
    int*            sorted_src = (int*)alloc((size_t)M * 4);
    unsigned short* qbuf    = (unsigned short*)alloc((size_t)S * 256 * 2);
    unsigned short* pooledn = (unsigned short*)alloc((size_t)S * 256 * 2);
    unsigned short* kvbuf   = (unsigned short*)alloc((size_t)M * 512 * 2);

    hipMemsetAsync(counts, 0, (size_t)S * 4, stream);
    hipMemsetAsync(cursor, 0, (size_t)S * 4, stream);

    convert_weights<<<(262144 + 512 + 255) / 256, 256, 0, stream>>>(
        W_q, W_k, W_v, W_o, b_k, b_v, Wt_q, Wt_kv, Wt_o, b_kv);

    // counting sort of mapping entries by segment
    hist_kernel<<<(M + 255) / 256, 256, 0, stream>>>(map_val, counts, M);
    scan_kernel<<<1, 1024, 0, stream>>>(counts, offsets, S);
    scatter_kernel<<<(M + 255) / 256, 256, 0, stream>>>(
        map_key, map_val, offsets, cursor, sorted_src, M);

    // Q projection: q[pdg_key[i]] = enc[pdg_val[i]] @ W_q + b_q
    dim3 gq(2, (S + 127) / 128);
    gemm_proj<true, true, false, false><<<gq, 256, 0, stream>>>(
        enc, pdg_val, pdg_key, Wt_q, b_q, qbuf, S, 256);

    // K|V projection in sorted-entry order: kv[i] = enc[sorted_src[i]] @ [W_k|W_v] + [b_k|b_v]
    dim3 gkv(4, (M + 127) / 128);
    gemm_proj<true, false, false, false><<<gkv, 256, 0, stream>>>(
        enc, sorted_src, nullptr, Wt_kv, b_kv, kvbuf, M, 512);

    // CSR segment softmax + weighted pooling + normalize (bf16 out)
    pool_csr_kernel<<<(S + 3) / 4, 256, 0, stream>>>(qbuf, kvbuf, offsets, pooledn, S);

    // output projection to d_out (fp32)
    dim3 go(2, (S + 127) / 128);
    gemm_proj<false, false, true, true><<<go, 256, 0, stream>>>(
        pooledn, nullptr, nullptr, Wt_o, b_o, d_out, S, 256);
}

// Round 3
// 807.843 us; speedup vs baseline: 2.8785x; 1.5023x over previous
//
#include <hip/hip_runtime.h>
#include <hip/hip_bf16.h>

// ---------------------------------------------------------------------------
// CFGSubASTExpressionCombiner: enc->bf16, counting-sort by segment,
// Q/K/V projections (bf16 MFMA, full-N 128x256 tiles, gather rows once),
// CSR segment softmax+pool (no atomics), output GEMM.
// D = 256, H = 8, HD = 32, OUT = 256.
// ---------------------------------------------------------------------------

typedef __attribute__((ext_vector_type(8))) short bf16x8;
typedef __attribute__((ext_vector_type(4))) float f32x4;

#define DEV __device__ __forceinline__

DEV float bf2f(unsigned short u) {
    union { unsigned int i; float f; } x;
    x.i = ((unsigned int)u) << 16;
    return x.f;
}

DEV unsigned short f2bf(float f) {
    union { float f; unsigned int i; } x;
    x.f = f;
    unsigned int i = x.i;
    unsigned int r = 0x7fffu + ((i >> 16) & 1u);   // round-to-nearest-even
    return (unsigned short)((i + r) >> 16);
}

// ---------------------------------------------------------------------------
// enc fp32 -> bf16 (grid-stride, float4 in / ushort4 out)
// ---------------------------------------------------------------------------
__global__ __launch_bounds__(256) void conv_enc(const float* __restrict__ in,
                                                unsigned short* __restrict__ out,
                                                int n4) {
    const int stride = gridDim.x * 256;
    for (int i = blockIdx.x * 256 + threadIdx.x; i < n4; i += stride) {
        const float4 v = ((const float4*)in)[i];
        ushort4 o;
        o.x = f2bf(v.x); o.y = f2bf(v.y); o.z = f2bf(v.z); o.w = f2bf(v.w);
        ((ushort4*)out)[i] = o;
    }
}

// ---------------------------------------------------------------------------
// Weight prep: transpose fp32 [K][N] weights into bf16 [N][K] layout.
// ---------------------------------------------------------------------------
__global__ void convert_weights(const float* __restrict__ Wq,
                                const float* __restrict__ Wk,
                                const float* __restrict__ Wv,
                                const float* __restrict__ Wo,
                                unsigned short* __restrict__ Wtq,
                                unsigned short* __restrict__ Wtk,
                                unsigned short* __restrict__ Wtv,
                                unsigned short* __restrict__ Wto) {
    int t = blockIdx.x * 256 + threadIdx.x;
    if (t >= 4 * 65536) return;
    int which = t >> 16;
    int u = t & 65535;
    int n = u >> 8, k = u & 255;
    const float* W = which == 0 ? Wq : which == 1 ? Wk : which == 2 ? Wv : Wo;
    unsigned short* Wt = which == 0 ? Wtq : which == 1 ? Wtk : which == 2 ? Wtv : Wto;
    Wt[u] = f2bf(W[k * 256 + n]);
}

// ---------------------------------------------------------------------------
// Counting sort of mapping entries by segment id.
// ---------------------------------------------------------------------------
__global__ void hist_kernel(const int* __restrict__ map_val,
                            int* __restrict__ counts, int M) {
    int m = blockIdx.x * 256 + threadIdx.x;
    if (m < M) atomicAdd(&counts[map_val[m]], 1);
}

// Single-block exclusive scan over counts[S] -> offsets[S+1].
__global__ __launch_bounds__(1024) void scan_kernel(const int* __restrict__ counts,
                                                    int* __restrict__ offsets, int S) {
    __shared__ int part[1024];
    const int t = threadIdx.x;
    const int chunk = (S + 1023) / 1024;
    const int lo = t * chunk;
    const int hi = min(lo + chunk, S);
    int sum = 0;
    for (int i = lo; i < hi; ++i) sum += counts[i];
    part[t] = sum;
    __syncthreads();
    for (int d = 1; d < 1024; d <<= 1) {
        int v = (t >= d) ? part[t - d] : 0;
        __syncthreads();
        part[t] += v;
        __syncthreads();
    }
    int run = (t > 0) ? part[t - 1] : 0;
    for (int i = lo; i < hi; ++i) {
        offsets[i] = run;
        run += counts[i];
    }
    if (t == 1023) offsets[S] = part[1023];
}

__global__ void scatter_kernel(const int* __restrict__ map_key,
                               const int* __restrict__ map_val,
                               const int* __restrict__ offsets,
                               int* __restrict__ cursor,
                               int* __restrict__ sorted_src, int M) {
    int m = blockIdx.x * 256 + threadIdx.x;
    if (m >= M) return;
    int seg = map_val[m];
    int pos = offsets[seg] + atomicAdd(&cursor[seg], 1);
    sorted_src[pos] = map_key[m];
}

// ---------------------------------------------------------------------------
// GEMM: Out[dst(r)][colOff+n] = sum_k A[src(r)][k] * Wt[n][k] + bias[n]
// A bf16 [*][256], Wt bf16 [256][256]. Tile 128(M) x 256(N), K=256 in 4x64.
// 512 threads = 8 waves, wave (wm,wn) in 2x4 grid owns a 64x64 quadrant.
// A rows fetched once per GEMM; next k-tile A prefetched into registers.
// ---------------------------------------------------------------------------
template <bool GATHER, bool SCATTER, bool OUT_F32>
__global__ __launch_bounds__(512) void gemm256(
    const unsigned short* __restrict__ A,
    const int* __restrict__ srcIdx,
    const int* __restrict__ dstIdx,
    const unsigned short* __restrict__ Wt,
    const float* __restrict__ bias,
    void* __restrict__ Out,
    int nrows, int ldo, int colOff) {
    __shared__ unsigned short Alds[128][72];
    __shared__ unsigned short Blds[256][72];

    const int tm = blockIdx.x;
    const int tid = threadIdx.x;
    const int wave = tid >> 6, lane = tid & 63;
    const int wm = wave >> 2, wn = wave & 3;

    const int c8 = (tid & 7) * 8;
    const int rb = tid >> 3;   // 0..63

    long src0, src1;
    {
        const int gr0 = tm * 128 + rb;
        const int gr1 = gr0 + 64;
        src0 = (gr0 < nrows) ? (GATHER ? (long)srcIdx[gr0] : (long)gr0) : 0;
        src1 = (gr1 < nrows) ? (GATHER ? (long)srcIdx[gr1] : (long)gr1) : 0;
    }
    const unsigned short* arow0 = A + src0 * 256 + c8;
    const unsigned short* arow1 = A + src1 * 256 + c8;

    f32x4 acc[4][4] = {};

    uint4 a0 = *(const uint4*)(arow0);
    uint4 a1 = *(const uint4*)(arow1);

    for (int kt = 0; kt < 4; ++kt) {
        const int k0 = kt * 64;

        // stage current k-tile
        *(uint4*)(&Alds[rb][c8])       = a0;
        *(uint4*)(&Alds[rb + 64][c8])  = a1;
        *(uint4*)(&Blds[rb][c8])       = *(const uint4*)(Wt + (long)(rb)       * 256 + k0 + c8);
        *(uint4*)(&Blds[rb + 64][c8])  = *(const uint4*)(Wt + (long)(rb + 64)  * 256 + k0 + c8);
        *(uint4*)(&Blds[rb + 128][c8]) = *(const uint4*)(Wt + (long)(rb + 128) * 256 + k0 + c8);
        *(uint4*)(&Blds[rb + 192][c8]) = *(const uint4*)(Wt + (long)(rb + 192) * 256 + k0 + c8);

        __syncthreads();

        // prefetch next k-tile of A while MFMA runs
        if (kt < 3) {
            a0 = *(const uint4*)(arow0 + k0 + 64);
            a1 = *(const uint4*)(arow1 + k0 + 64);
        }

#pragma unroll
        for (int ks = 0; ks < 2; ++ks) {
            const int kb = ks * 32 + (lane >> 4) * 8;
            bf16x8 a[4], b[4];
#pragma unroll
            for (int i = 0; i < 4; ++i)
                a[i] = *(const bf16x8*)(&Alds[wm * 64 + i * 16 + (lane & 15)][kb]);
#pragma unroll
            for (int j = 0; j < 4; ++j)
                b[j] = *(const bf16x8*)(&Blds[wn * 64 + j * 16 + (lane & 15)][kb]);
#pragma unroll
            for (int i = 0; i < 4; ++i)
#pragma unroll
                for (int j = 0; j < 4; ++j)
                    acc[i][j] = __builtin_amdgcn_mfma_f32_16x16x32_bf16(a[i], b[j], acc[i][j], 0, 0, 0);
        }

        __syncthreads();
    }

    // ---- epilogue ----
#pragma unroll
    for (int i = 0; i < 4; ++i) {
#pragma unroll
        for (int j = 0; j < 4; ++j) {
            const int lcol = wn * 64 + j * 16 + (lane & 15);
            const float bs = bias[lcol];
            const int col = colOff + lcol;
#pragma unroll
            for (int rj = 0; rj < 4; ++rj) {
                const int row = tm * 128 + wm * 64 + i * 16 + (lane >> 4) * 4 + rj;
                if (row < nrows) {
                    long drow = SCATTER ? (long)dstIdx[row] : (long)row;
                    float val = acc[i][j][rj] + bs;
                    if constexpr (OUT_F32)
                        ((float*)Out)[drow * ldo + col] = val;
                    else
                        ((unsigned short*)Out)[drow * ldo + col] = f2bf(val);
                }
            }
        }
    }
}

// ---------------------------------------------------------------------------
// CSR pooling: one wave per segment s; kv rows for s are [offsets[s],offsets[s+1]).
// score_h = <k[e,h,:], q[s,h,:]>*scale ; ew = exp(score) (shift-free; |score|<~1)
// pooled[s] = sum ew*v / sum ew, written bf16 IN PLACE over q[s].
// ---------------------------------------------------------------------------
__global__ __launch_bounds__(256) void pool_csr_kernel(
    unsigned short* __restrict__ q,          // bf16 [S][256] (in: q, out: pooled)
    const unsigned short* __restrict__ kv,   // bf16 [Msorted][512] (k | v)
    const int* __restrict__ offsets,         // [S+1]
    int S) {
    const int s = blockIdx.x * 4 + (threadIdx.x >> 6);
    if (s >= S) return;
    const int lane = threadIdx.x & 63;
    const int beg = offsets[s];
    const int end = offsets[s + 1];

    const ushort4 qv = *(const ushort4*)(q + (long)s * 256 + lane * 4);
    const float q0 = bf2f(qv.x), q1 = bf2f(qv.y), q2 = bf2f(qv.z), q3 = bf2f(qv.w);

    float a0 = 0.f, a1 = 0.f, a2 = 0.f, a3 = 0.f, denom = 0.f;

    for (int e = beg; e < end; ++e) {
        const ushort4 kk = *(const ushort4*)(kv + (long)e * 512 + lane * 4);
        const ushort4 vv = *(const ushort4*)(kv + (long)e * 512 + 256 + lane * 4);
        float p = q0 * bf2f(kk.x) + q1 * bf2f(kk.y) + q2 * bf2f(kk.z) + q3 * bf2f(kk.w);
        p += __shfl_xor(p, 1);
        p += __shfl_xor(p, 2);
        p += __shfl_xor(p, 4);   // 8-lane head group holds the head dot
        const float ew = expf(p * 0.17677669529663687f);  // 1/sqrt(32)
        a0 += ew * bf2f(vv.x);
        a1 += ew * bf2f(vv.y);
        a2 += ew * bf2f(vv.z);
        a3 += ew * bf2f(vv.w);
        denom += ew;
    }

    const float w = 1.0f / fmaxf(denom, 1e-9f);
    ushort4 o;
    o.x = f2bf(a0 * w);
    o.y = f2bf(a1 * w);
    o.z = f2bf(a2 * w);
    o.w = f2bf(a3 * w);
    *(ushort4*)(q + (long)s * 256 + lane * 4) = o;
}

// ---------------------------------------------------------------------------
extern "C" void kernel_launch(void* const* d_in, const int* in_sizes, int n_in,
                              void* d_out, int out_size, void* d_ws, size_t ws_size,
                              hipStream_t stream) {
    const float* enc  = (const float*)d_in[0];
    const float* W_q  = (const float*)d_in[1];
    const float* b_q  = (const float*)d_in[2];
    const float* W_k  = (const float*)d_in[3];
    const float* b_k  = (const float*)d_in[4];
    const float* W_v  = (const float*)d_in[5];
    const float* b_v  = (const float*)d_in[6];
    const float* W_o  = (const float*)d_in[7];
    const float* b_o  = (const float*)d_in[8];
    const int* map_key = (const int*)d_in[9];    // [M] ast idx
    const int* map_val = (const int*)d_in[10];   // [M] cfg idx (segment id)
    const int* pdg_key = (const int*)d_in[11];   // [S] dst rows (bijection)
    const int* pdg_val = (const int*)d_in[12];   // [S] src ast rows

    const int M = in_sizes[9];
    const int S = in_sizes[11];
    const int NAST = in_sizes[0] / 256;

    char* ws = (char*)d_ws;
    size_t off = 0;
    auto alloc = [&](size_t bytes) -> char* {
        char* p = ws + off;
        off += (bytes + 255) & ~(size_t)255;
        return p;
    };

    unsigned short* Wt_q  = (unsigned short*)alloc(256 * 256 * 2);
    unsigned short* Wt_k  = (unsigned short*)alloc(256 * 256 * 2);
    unsigned short* Wt_v  = (unsigned short*)alloc(256 * 256 * 2);
    unsigned short* Wt_o  = (unsigned short*)alloc(256 * 256 * 2);
    int*            counts  = (int*)alloc((size_t)S * 4);
    int*            cursor  = (int*)alloc((size_t)S * 4);
    int*            offsets = (int*)alloc((size_t)(S + 1) * 4);
    int*            sorted_src = (int*)alloc((size_t)M * 4);
    unsigned short* enc16 = (unsigned short*)alloc((size_t)NAST * 256 * 2);
    unsigned short* qbuf  = (unsigned short*)alloc((size_t)S * 256 * 2);  // q, then pooled
    unsigned short* kvbuf = (unsigned short*)alloc((size_t)M * 512 * 2);

    hipMemsetAsync(counts, 0, (size_t)S * 4, stream);
    hipMemsetAsync(cursor, 0, (size_t)S * 4, stream);

    conv_enc<<<2048, 256, 0, stream>>>(enc, enc16, NAST * 64);

    convert_weights<<<1024, 256, 0, stream>>>(W_q, W_k, W_v, W_o, Wt_q, Wt_k, Wt_v, Wt_o);

    // counting sort of mapping entries by segment
    hist_kernel<<<(M + 255) / 256, 256, 0, stream>>>(map_val, counts, M);
    scan_kernel<<<1, 1024, 0, stream>>>(counts, offsets, S);
    scatter_kernel<<<(M + 255) / 256, 256, 0, stream>>>(
        map_key, map_val, offsets, cursor, sorted_src, M);

    // Q projection: q[pdg_key[i]] = enc16[pdg_val[i]] @ W_q + b_q
    gemm256<true, true, false><<<(S + 127) / 128, 512, 0, stream>>>(
        enc16, pdg_val, pdg_key, Wt_q, b_q, qbuf, S, 256, 0);

    // K projection into kv[:, 0:256]
    gemm256<true, false, false><<<(M + 127) / 128, 512, 0, stream>>>(
        enc16, sorted_src, nullptr, Wt_k, b_k, kvbuf, M, 512, 0);

    // V projection into kv[:, 256:512]
    gemm256<true, false, false><<<(M + 127) / 128, 512, 0, stream>>>(
        enc16, sorted_src, nullptr, Wt_v, b_v, kvbuf, M, 512, 256);

    // CSR segment softmax + pooling; pooled overwrites qbuf
    pool_csr_kernel<<<(S + 3) / 4, 256, 0, stream>>>(qbuf, kvbuf, offsets, S);

    // output projection to d_out (fp32)
    gemm256<false, false, true><<<(S + 127) / 128, 512, 0, stream>>>(
        qbuf, nullptr, nullptr, Wt_o, b_o, d_out, S, 256, 0);
}